// Round 1
// baseline (237.904 us; speedup 1.0000x reference)
//
#include <hip/hip_runtime.h>
#include <hip/hip_bf16.h>

// Problem constants: B=16, H=64, W=64, C=192, heads=8, key_dim=32, ks=3
// pixels = 16*64*64 = 65536; model dim = 256; kv input dim = 194.

typedef __bf16 bf16x8_t __attribute__((ext_vector_type(8)));
typedef float f32x4_t __attribute__((ext_vector_type(4)));

static __device__ __forceinline__ unsigned short bfbits(float f) {
    return __builtin_bit_cast(unsigned short, __float2bfloat16(f));
}
static __device__ __forceinline__ float bf2f(unsigned short u) {
    return __bfloat162float(__builtin_bit_cast(__hip_bfloat16, u));
}

// ---------------------------------------------------------------- convert x -> bf16
__global__ void k_convert_x(const float* __restrict__ x, ushort4* __restrict__ xb, int n4) {
    int i = blockIdx.x * blockDim.x + threadIdx.x;
    const int stride = gridDim.x * blockDim.x;
    const float4* x4 = reinterpret_cast<const float4*>(x);
    for (; i < n4; i += stride) {
        float4 v = x4[i];
        ushort4 o;
        o.x = bfbits(v.x); o.y = bfbits(v.y); o.z = bfbits(v.z); o.w = bfbits(v.w);
        xb[i] = o;
    }
}

// ---------------------------------------------------------------- pack weights
// WqkvT[m][k], m in [0,768): m<256 -> Wq, <512 -> Wk(x-rows), else Wv(x-rows). k in [0,192).
// WoT[c][hd] = Wo[hd][c].
// biasK[n][m] = dj*Wk[192][m] + di*Wk[193][m] + bk[m]  (n = i*3+j, di=i-1, dj=j-1)
__global__ void k_pack(const float* __restrict__ Wq, const float* __restrict__ Wk,
                       const float* __restrict__ Wv, const float* __restrict__ Wo,
                       const float* __restrict__ bk, const float* __restrict__ bv,
                       __hip_bfloat16* __restrict__ WqkvT, __hip_bfloat16* __restrict__ WoT,
                       float* __restrict__ biasK, float* __restrict__ biasV) {
    const int idx = blockIdx.x * blockDim.x + threadIdx.x;
    if (idx < 768 * 192) {
        const int m = idx / 192, k = idx % 192;
        float v;
        if (m < 256)      v = Wq[k * 256 + m];
        else if (m < 512) v = Wk[k * 256 + (m - 256)];
        else              v = Wv[k * 256 + (m - 512)];
        WqkvT[m * 192 + k] = __float2bfloat16(v);
    } else if (idx < 768 * 192 + 192 * 256) {
        const int j = idx - 768 * 192;
        const int c = j >> 8, hd = j & 255;
        WoT[j] = __float2bfloat16(Wo[hd * 192 + c]);
    } else if (idx < 768 * 192 + 192 * 256 + 2 * 9 * 256) {
        const int j = idx - (768 * 192 + 192 * 256);
        const int which = (j >= 9 * 256) ? 1 : 0;
        const int j2 = j - which * 9 * 256;
        const int n = j2 >> 8, m = j2 & 255;
        const float dj = (float)(n % 3 - 1);
        const float di = (float)(n / 3 - 1);
        if (!which) biasK[j2] = dj * Wk[192 * 256 + m] + di * Wk[193 * 256 + m] + bk[m];
        else        biasV[j2] = dj * Wv[192 * 256 + m] + di * Wv[193 * 256 + m] + bv[m];
    }
}

// ---------------------------------------------------------------- MFMA GEMM (B^T input)
// C[row][col] = sum_k A[row][k] * BT[col][k]  (+ bias[col]); A,BT bf16 row-major K-contig.
// Fragment layouts (m89/m91-verified): A/B lane reads 8 contiguous k at row (lane&15),
// k-block (lane>>4)*8; C/D: col = lane&15, row = (lane>>4)*4 + reg.
template<int BR, int BC, int WRN, int WCN, int KDIM, bool OUTF32, bool BIAS>
__global__ void k_gemm_bt(const __hip_bfloat16* __restrict__ A,
                          const __hip_bfloat16* __restrict__ BT,
                          void* __restrict__ Cout,
                          const float* __restrict__ bias, int ldc) {
    constexpr int WTR = BR / WRN;
    constexpr int WTC = BC / WCN;
    constexpr int FR = WTR / 16;
    constexpr int FC = WTC / 16;
    const int wave = threadIdx.x >> 6;
    const int lane = threadIdx.x & 63;
    const int wr = wave / WCN, wc = wave % WCN;
    const long rowBase = (long)blockIdx.y * BR + wr * WTR;
    const long colBase = (long)blockIdx.x * BC + wc * WTC;
    const int lr = lane & 15;
    const int lk = lane >> 4;

    f32x4_t acc[FR][FC] = {};
    #pragma unroll
    for (int k0 = 0; k0 < KDIM; k0 += 32) {
        bf16x8_t a[FR], b[FC];
        #pragma unroll
        for (int fr = 0; fr < FR; ++fr)
            a[fr] = *reinterpret_cast<const bf16x8_t*>(A + (rowBase + fr * 16 + lr) * KDIM + k0 + lk * 8);
        #pragma unroll
        for (int fc = 0; fc < FC; ++fc)
            b[fc] = *reinterpret_cast<const bf16x8_t*>(BT + (colBase + fc * 16 + lr) * KDIM + k0 + lk * 8);
        #pragma unroll
        for (int fr = 0; fr < FR; ++fr) {
            #pragma unroll
            for (int fc = 0; fc < FC; ++fc)
                acc[fr][fc] = __builtin_amdgcn_mfma_f32_16x16x32_bf16(a[fr], b[fc], acc[fr][fc], 0, 0, 0);
        }
    }
    const int rowSub = (lane >> 4) * 4;
    const int colSub = lane & 15;
    #pragma unroll
    for (int fr = 0; fr < FR; ++fr) {
        #pragma unroll
        for (int fc = 0; fc < FC; ++fc) {
            #pragma unroll
            for (int r = 0; r < 4; ++r) {
                const long row = rowBase + fr * 16 + rowSub + r;
                const long col = colBase + fc * 16 + colSub;
                float v = acc[fr][fc][r];
                if constexpr (BIAS) v += bias[col];
                if constexpr (OUTF32) ((float*)Cout)[row * ldc + col] = v;
                else ((__hip_bfloat16*)Cout)[row * ldc + col] = __float2bfloat16(v);
            }
        }
    }
}

// ---------------------------------------------------------------- attention gather
// One wave per pixel. Lane (h = lane>>3, dg = lane&7) owns dims idx = h*32 + dg*4 .. +4.
// QKV row layout: [q(256) | k'(256) | v'(256)], stride 768, bf16.
__global__ void k_attn(const __hip_bfloat16* __restrict__ QKV,
                       const float* __restrict__ bq,
                       const float* __restrict__ biasK,
                       const float* __restrict__ biasV,
                       __hip_bfloat16* __restrict__ O) {
    const int wave = threadIdx.x >> 6;
    const int lane = threadIdx.x & 63;
    const int p = blockIdx.x * 4 + wave;
    const int b = p >> 12;
    const int y = (p >> 6) & 63;
    const int xq = p & 63;
    const int idx = (lane >> 3) * 32 + (lane & 7) * 4;

    const ushort4 qu = *reinterpret_cast<const ushort4*>(QKV + (size_t)p * 768 + idx);
    const float4 bqv = *reinterpret_cast<const float4*>(bq + idx);
    const float scale = 0.17677669529663687f;  // 1/sqrt(32)
    const float q0 = (bf2f(qu.x) + bqv.x) * scale;
    const float q1 = (bf2f(qu.y) + bqv.y) * scale;
    const float q2 = (bf2f(qu.z) + bqv.z) * scale;
    const float q3 = (bf2f(qu.w) + bqv.w) * scale;

    float vreg[9][4];
    float sc[9];
    #pragma unroll
    for (int n = 0; n < 9; ++n) {
        const int di = n / 3 - 1, dj = n % 3 - 1;
        const int ny = y + di, nx = xq + dj;
        const bool inb = ((unsigned)ny < 64u) && ((unsigned)nx < 64u);
        float kk0 = 0.f, kk1 = 0.f, kk2 = 0.f, kk3 = 0.f;
        float vv0 = 0.f, vv1 = 0.f, vv2 = 0.f, vv3 = 0.f;
        if (inb) {
            const size_t nb = ((size_t)((b << 12) | (ny << 6) | nx)) * 768;
            const ushort4 ku = *reinterpret_cast<const ushort4*>(QKV + nb + 256 + idx);
            const ushort4 vu = *reinterpret_cast<const ushort4*>(QKV + nb + 512 + idx);
            kk0 = bf2f(ku.x); kk1 = bf2f(ku.y); kk2 = bf2f(ku.z); kk3 = bf2f(ku.w);
            vv0 = bf2f(vu.x); vv1 = bf2f(vu.y); vv2 = bf2f(vu.z); vv3 = bf2f(vu.w);
        }
        const float4 bk4 = *reinterpret_cast<const float4*>(biasK + n * 256 + idx);
        const float4 bv4 = *reinterpret_cast<const float4*>(biasV + n * 256 + idx);
        kk0 += bk4.x; kk1 += bk4.y; kk2 += bk4.z; kk3 += bk4.w;
        vv0 += bv4.x; vv1 += bv4.y; vv2 += bv4.z; vv3 += bv4.w;
        vreg[n][0] = vv0; vreg[n][1] = vv1; vreg[n][2] = vv2; vreg[n][3] = vv3;
        float partial = q0 * kk0 + q1 * kk1 + q2 * kk2 + q3 * kk3;
        partial += __shfl_xor(partial, 1);
        partial += __shfl_xor(partial, 2);
        partial += __shfl_xor(partial, 4);
        sc[n] = partial;  // all 8 lanes of this head hold score[n]
    }
    float mx = sc[0];
    #pragma unroll
    for (int n = 1; n < 9; ++n) mx = fmaxf(mx, sc[n]);
    float sum = 0.f;
    #pragma unroll
    for (int n = 0; n < 9; ++n) { sc[n] = __expf(sc[n] - mx); sum += sc[n]; }
    const float inv = 1.0f / sum;
    float o0 = 0.f, o1 = 0.f, o2 = 0.f, o3 = 0.f;
    #pragma unroll
    for (int n = 0; n < 9; ++n) {
        o0 += sc[n] * vreg[n][0];
        o1 += sc[n] * vreg[n][1];
        o2 += sc[n] * vreg[n][2];
        o3 += sc[n] * vreg[n][3];
    }
    ushort4 ov;
    ov.x = bfbits(o0 * inv); ov.y = bfbits(o1 * inv);
    ov.z = bfbits(o2 * inv); ov.w = bfbits(o3 * inv);
    *reinterpret_cast<ushort4*>(O + (size_t)p * 256 + idx) = ov;
}

// ---------------------------------------------------------------- launch
extern "C" void kernel_launch(void* const* d_in, const int* in_sizes, int n_in,
                              void* d_out, int out_size, void* d_ws, size_t ws_size,
                              hipStream_t stream) {
    (void)in_sizes; (void)n_in; (void)out_size; (void)ws_size;
    const float* x  = (const float*)d_in[0];
    const float* Wq = (const float*)d_in[1];
    const float* bq = (const float*)d_in[2];
    const float* Wk = (const float*)d_in[3];
    const float* bk = (const float*)d_in[4];
    const float* Wv = (const float*)d_in[5];
    const float* bv = (const float*)d_in[6];
    const float* Wo = (const float*)d_in[7];
    const float* bo = (const float*)d_in[8];

    char* ws = (char*)d_ws;
    // ws layout (bytes, 256-aligned):
    __hip_bfloat16* xb    = (__hip_bfloat16*)(ws + 0);          // 12582912 * 2 = 25165824
    __hip_bfloat16* WqkvT = (__hip_bfloat16*)(ws + 25165824);   // 768*192*2   = 294912
    __hip_bfloat16* WoT   = (__hip_bfloat16*)(ws + 25460736);   // 192*256*2   = 98304
    float* biasK          = (float*)(ws + 25559040);            // 9*256*4     = 9216
    float* biasV          = (float*)(ws + 25568256);            // 9*256*4     = 9216
    __hip_bfloat16* QKV   = (__hip_bfloat16*)(ws + 25577472);   // 65536*768*2 = 100663296
    __hip_bfloat16* O     = (__hip_bfloat16*)(ws + 126240768);  // 65536*256*2 = 33554432
    // total = 159795200 bytes

    k_convert_x<<<4096, 256, 0, stream>>>(x, (ushort4*)xb, 12582912 / 4);
    k_pack<<<786, 256, 0, stream>>>(Wq, Wk, Wv, Wo, bk, bv, WqkvT, WoT, biasK, biasV);
    // QKV projection: [65536,192] x [192,768] -> [65536,768] bf16
    k_gemm_bt<128, 128, 2, 2, 192, false, false>
        <<<dim3(6, 512), 256, 0, stream>>>(xb, WqkvT, (void*)QKV, nullptr, 768);
    // attention: 65536 pixels, one wave each
    k_attn<<<16384, 256, 0, stream>>>(QKV, bq, biasK, biasV, O);
    // output projection: [65536,256] x [256,192] -> [65536,192] f32 + bo
    k_gemm_bt<128, 64, 4, 1, 256, true, true>
        <<<dim3(3, 512), 256, 0, stream>>>(O, WoT, d_out, bo, 192);
}

// Round 3
// 164.365 us; speedup vs baseline: 1.4474x; 1.4474x over previous
//
#include <hip/hip_runtime.h>
#include <hip/hip_bf16.h>

// B=16, H=64, W=64, C=192, heads=8, key_dim=32, ks=3
// pixels = 65536; model dim = 256; QKV row = [q(256)|k(256)|v(256)|qb(72)] stride 840.
// Zero row at pixel index 65536 handles OOB neighbors (k'=v'=0 -> score=qb, v=biasV).

typedef __bf16 bf16x8_t __attribute__((ext_vector_type(8)));
typedef float f32x4_t __attribute__((ext_vector_type(4)));

#define SCALE 0.17677669529663687f
#define QSTRIDE 840
#define ZROW 65536

static __device__ __forceinline__ unsigned short bfbits(float f) {
    return __builtin_bit_cast(unsigned short, __float2bfloat16(f));
}
static __device__ __forceinline__ float bf2f(unsigned short u) {
    return __bfloat162float(__builtin_bit_cast(__hip_bfloat16, u));
}

static __device__ __forceinline__ void gload_lds16(const void* g, void* l) {
    __builtin_amdgcn_global_load_lds((const __attribute__((address_space(1))) void*)g,
                                     (__attribute__((address_space(3))) void*)l, 16, 0, 0);
}

// ---------------------------------------------------------------- convert x -> bf16
__global__ void k_convert_x(const float* __restrict__ x, ushort4* __restrict__ xb, int n4) {
    int i = blockIdx.x * blockDim.x + threadIdx.x;
    const int stride = gridDim.x * blockDim.x;
    const float4* x4 = reinterpret_cast<const float4*>(x);
    for (; i < n4; i += stride) {
        float4 v = x4[i];
        ushort4 o;
        o.x = bfbits(v.x); o.y = bfbits(v.y); o.z = bfbits(v.z); o.w = bfbits(v.w);
        xb[i] = o;
    }
}

// ---------------------------------------------------------------- pack weights
// WqkvT[896][192]: m<256 Wq*scale; <512 Wk(x); <768 Wv(x); <840 Wqb = scale*Wq·biasK; else 0
// WoT[192][256]; biasV[9][256] f32; qkvBias[896] f32; zero QKV row 65536.
__global__ void k_pack(const float* __restrict__ Wq, const float* __restrict__ Wk,
                       const float* __restrict__ Wv, const float* __restrict__ Wo,
                       const float* __restrict__ bq, const float* __restrict__ bk,
                       const float* __restrict__ bv,
                       __hip_bfloat16* __restrict__ WqkvT, __hip_bfloat16* __restrict__ WoT,
                       float* __restrict__ biasV, float* __restrict__ qkvBias,
                       __hip_bfloat16* __restrict__ QKV) {
    const int idx = blockIdx.x * blockDim.x + threadIdx.x;
    const int T0 = 896 * 192;            // WqkvT
    const int T1 = T0 + 192 * 256;       // WoT
    const int T2 = T1 + 9 * 256;         // biasV
    const int T3 = T2 + 896;             // qkvBias
    const int T4 = T3 + QSTRIDE;         // zero row
    if (idx < T0) {
        const int m = idx / 192, k = idx % 192;
        float v;
        if (m < 256)      v = Wq[k * 256 + m] * SCALE;
        else if (m < 512) v = Wk[k * 256 + (m - 256)];
        else if (m < 768) v = Wv[k * 256 + (m - 512)];
        else if (m < 840) {
            const int j = m - 768, h = j / 9, n = j % 9;
            const float dj = (float)(n % 3 - 1), di = (float)(n / 3 - 1);
            float acc = 0.f;
            for (int d = 0; d < 32; ++d) {
                const int c = h * 32 + d;
                const float bkv = dj * Wk[192 * 256 + c] + di * Wk[193 * 256 + c] + bk[c];
                acc += Wq[k * 256 + c] * bkv;
            }
            v = acc * SCALE;
        } else v = 0.f;
        WqkvT[m * 192 + k] = __float2bfloat16(v);
    } else if (idx < T1) {
        const int j = idx - T0;
        const int c = j >> 8, hd = j & 255;
        WoT[j] = __float2bfloat16(Wo[hd * 192 + c]);
    } else if (idx < T2) {
        const int j = idx - T1;
        const int n = j >> 8, m = j & 255;
        const float dj = (float)(n % 3 - 1), di = (float)(n / 3 - 1);
        biasV[j] = dj * Wv[192 * 256 + m] + di * Wv[193 * 256 + m] + bv[m];
    } else if (idx < T3) {
        const int col = idx - T2;
        float v = 0.f;
        if (col < 256) v = bq[col] * SCALE;
        else if (col >= 768 && col < 840) {
            const int j = col - 768, h = j / 9, n = j % 9;
            const float dj = (float)(n % 3 - 1), di = (float)(n / 3 - 1);
            float acc = 0.f;
            for (int d = 0; d < 32; ++d) {
                const int c = h * 32 + d;
                const float bkv = dj * Wk[192 * 256 + c] + di * Wk[193 * 256 + c] + bk[c];
                acc += bq[c] * bkv;
            }
            v = acc * SCALE;
        }
        qkvBias[col] = v;
    } else if (idx < T4) {
        const int j = idx - T3;
        QKV[(size_t)ZROW * QSTRIDE + j] = __float2bfloat16(0.f);
    }
}

// ---------------------------------------------------------------- LDS-staged MFMA GEMM
// C[row][col] = sum_k A[row][k]*BT[col][k] (+bias[col]); A,BT bf16 K-contig.
// m97 structure: global_load_lds width16, BK=64, 2-barrier loop.
template<int BM, int BN, int WRN, int WCN, int KDIM, int NOUT, bool OUTF32, bool BIAS>
__global__ __launch_bounds__(256) void k_gemm_lds(const __hip_bfloat16* __restrict__ A,
                          const __hip_bfloat16* __restrict__ BT,
                          void* __restrict__ Cout,
                          const float* __restrict__ bias, int ldc) {
    constexpr int WTR = BM / WRN;
    constexpr int WTC = BN / WCN;
    constexpr int FR = WTR / 16;
    constexpr int FC = WTC / 16;
    constexpr int NK = KDIM / 64;
    __shared__ __hip_bfloat16 sA[BM * 64];
    __shared__ __hip_bfloat16 sB[BN * 64];
    const int tid = threadIdx.x;
    const int wave = tid >> 6, lane = tid & 63;
    const int wr = wave / WCN, wc = wave % WCN;
    const long rowBase = (long)blockIdx.y * BM;
    const long colBase = (long)blockIdx.x * BN;
    const int lr = lane & 15, lk = lane >> 4;
    const int srow = lane >> 3;              // 0..7 within the wave's 8-row chunk
    const int scol = (lane & 7) * 8;         // k-element offset of this lane's 16B

    f32x4_t acc[FR][FC] = {};
    for (int t = 0; t < NK; ++t) {
        const int k0 = t * 64;
        // stage A: BM/32 rounds of 32 rows (4 waves x 8 rows, 1KB/wave-issue)
        #pragma unroll
        for (int r = 0; r < BM / 32; ++r) {
            const int row0 = r * 32 + wave * 8;
            gload_lds16(A + (rowBase + row0 + srow) * KDIM + k0 + scol, sA + row0 * 64);
        }
        #pragma unroll
        for (int r = 0; r < BN / 32; ++r) {
            const int row0 = r * 32 + wave * 8;
            gload_lds16(BT + (colBase + row0 + srow) * KDIM + k0 + scol, sB + row0 * 64);
        }
        __syncthreads();
        #pragma unroll
        for (int kk = 0; kk < 64; kk += 32) {
            bf16x8_t a[FR], b[FC];
            #pragma unroll
            for (int fr = 0; fr < FR; ++fr)
                a[fr] = *reinterpret_cast<const bf16x8_t*>(sA + (wr * WTR + fr * 16 + lr) * 64 + kk + lk * 8);
            #pragma unroll
            for (int fc = 0; fc < FC; ++fc)
                b[fc] = *reinterpret_cast<const bf16x8_t*>(sB + (wc * WTC + fc * 16 + lr) * 64 + kk + lk * 8);
            #pragma unroll
            for (int fr = 0; fr < FR; ++fr) {
                #pragma unroll
                for (int fc = 0; fc < FC; ++fc)
                    acc[fr][fc] = __builtin_amdgcn_mfma_f32_16x16x32_bf16(a[fr], b[fc], acc[fr][fc], 0, 0, 0);
            }
        }
        __syncthreads();
    }
    const int rowSub = (lane >> 4) * 4;
    const int colSub = lane & 15;
    #pragma unroll
    for (int fr = 0; fr < FR; ++fr) {
        #pragma unroll
        for (int fc = 0; fc < FC; ++fc) {
            const long col = colBase + wc * WTC + fc * 16 + colSub;
            if (col >= NOUT) continue;
            float bv = BIAS ? bias[col] : 0.f;
            #pragma unroll
            for (int r = 0; r < 4; ++r) {
                const long row = rowBase + wr * WTR + fr * 16 + rowSub + r;
                float v = acc[fr][fc][r] + bv;
                if constexpr (OUTF32) ((float*)Cout)[row * ldc + col] = v;
                else ((__hip_bfloat16*)Cout)[row * ldc + col] = __float2bfloat16(v);
            }
        }
    }
}

// ---------------------------------------------------------------- attention gather
// One wave per pixel. lane: h=lane>>3 (head), dg=lane&7 -> dims idx=h*32+dg*4..+4.
// score_n = q_s . k'_n + qb_n ; OOB -> zero row -> score = qb_n exactly.
__global__ __launch_bounds__(256) void k_attn(const __hip_bfloat16* __restrict__ QKV,
                       const float* __restrict__ biasV,
                       __hip_bfloat16* __restrict__ O) {
    const int wave = threadIdx.x >> 6;
    const int lane = threadIdx.x & 63;
    const int p = blockIdx.x * 4 + wave;
    const int y = (p >> 6) & 63;
    const int xq = p & 63;
    const int h = lane >> 3;
    const int idx = h * 32 + (lane & 7) * 4;
    const __hip_bfloat16* rowQ = QKV + (size_t)p * QSTRIDE;

    const ushort4 qu = *reinterpret_cast<const ushort4*>(rowQ + idx);
    const float q0 = bf2f(qu.x), q1 = bf2f(qu.y), q2 = bf2f(qu.z), q3 = bf2f(qu.w);

    float qb[9];
    #pragma unroll
    for (int n = 0; n < 9; ++n)
        qb[n] = __bfloat162float(rowQ[768 + h * 9 + n]);

    // branch-free neighbor loads (OOB -> zero row), all issued up front
    ushort4 ku[9], vu[9];
    #pragma unroll
    for (int n = 0; n < 9; ++n) {
        const int di = n / 3 - 1, dj = n % 3 - 1;
        const int ny = y + di, nx = xq + dj;
        const bool inb = ((unsigned)ny < 64u) & ((unsigned)nx < 64u);
        const size_t np = inb ? (size_t)(p + di * 64 + dj) : (size_t)ZROW;
        const __hip_bfloat16* base = QKV + np * QSTRIDE;
        ku[n] = *reinterpret_cast<const ushort4*>(base + 256 + idx);
        vu[n] = *reinterpret_cast<const ushort4*>(base + 512 + idx);
    }

    float sc[9];
    #pragma unroll
    for (int n = 0; n < 9; ++n) {
        float s = q0 * bf2f(ku[n].x) + q1 * bf2f(ku[n].y) + q2 * bf2f(ku[n].z) + q3 * bf2f(ku[n].w);
        s += __shfl_xor(s, 1);
        s += __shfl_xor(s, 2);
        s += __shfl_xor(s, 4);
        sc[n] = s + qb[n];
    }
    float mx = sc[0];
    #pragma unroll
    for (int n = 1; n < 9; ++n) mx = fmaxf(mx, sc[n]);
    float sum = 0.f;
    #pragma unroll
    for (int n = 0; n < 9; ++n) { sc[n] = __expf(sc[n] - mx); sum += sc[n]; }
    const float inv = 1.0f / sum;

    float o0 = 0.f, o1 = 0.f, o2 = 0.f, o3 = 0.f;
    #pragma unroll
    for (int n = 0; n < 9; ++n) {
        const float4 bv4 = *reinterpret_cast<const float4*>(biasV + n * 256 + idx);
        o0 += sc[n] * (bf2f(vu[n].x) + bv4.x);
        o1 += sc[n] * (bf2f(vu[n].y) + bv4.y);
        o2 += sc[n] * (bf2f(vu[n].z) + bv4.z);
        o3 += sc[n] * (bf2f(vu[n].w) + bv4.w);
    }
    ushort4 ov;
    ov.x = bfbits(o0 * inv); ov.y = bfbits(o1 * inv);
    ov.z = bfbits(o2 * inv); ov.w = bfbits(o3 * inv);
    *reinterpret_cast<ushort4*>(O + (size_t)p * 256 + idx) = ov;
}

// ---------------------------------------------------------------- launch
extern "C" void kernel_launch(void* const* d_in, const int* in_sizes, int n_in,
                              void* d_out, int out_size, void* d_ws, size_t ws_size,
                              hipStream_t stream) {
    (void)in_sizes; (void)n_in; (void)out_size; (void)ws_size;
    const float* x  = (const float*)d_in[0];
    const float* Wq = (const float*)d_in[1];
    const float* bq = (const float*)d_in[2];
    const float* Wk = (const float*)d_in[3];
    const float* bk = (const float*)d_in[4];
    const float* Wv = (const float*)d_in[5];
    const float* bv = (const float*)d_in[6];
    const float* Wo = (const float*)d_in[7];
    const float* bo = (const float*)d_in[8];

    char* ws = (char*)d_ws;
    // ws layout (O overlaps dead xb; total ~144.2 MB):
    __hip_bfloat16* xb    = (__hip_bfloat16*)(ws + 0);           // 25,165,824 B
    __hip_bfloat16* O     = (__hip_bfloat16*)(ws + 0);           // 33,554,432 B (after xb dead)
    __hip_bfloat16* QKV   = (__hip_bfloat16*)(ws + 33554432);    // 65537*840*2 = 110,102,160 B
    __hip_bfloat16* WqkvT = (__hip_bfloat16*)(ws + 143656704);   // 896*192*2 = 344,064
    __hip_bfloat16* WoT   = (__hip_bfloat16*)(ws + 144000768);   // 192*256*2 = 98,304
    float* qkvBias        = (float*)(ws + 144099072);            // 896*4 = 3,584
    float* biasV          = (float*)(ws + 144102656);            // 9*256*4 = 9,216

    k_convert_x<<<4096, 256, 0, stream>>>(x, (ushort4*)xb, 12582912 / 4);
    k_pack<<<880, 256, 0, stream>>>(Wq, Wk, Wv, Wo, bq, bk, bv, WqkvT, WoT, biasV, qkvBias, QKV);
    // QKV+QB projection: [65536,192] x [192,896(840 used)] -> bf16, stride 840
    k_gemm_lds<128, 128, 2, 2, 192, 840, false, true>
        <<<dim3(7, 512), 256, 0, stream>>>(xb, WqkvT, (void*)QKV, qkvBias, QSTRIDE);
    // attention: one wave per pixel
    k_attn<<<16384, 256, 0, stream>>>(QKV, biasV, O);
    // output projection: [65536,256] x [256,192] -> f32 + bo
    k_gemm_lds<128, 64, 2, 2, 256, 192, true, true>
        <<<dim3(3, 512), 256, 0, stream>>>(O, WoT, d_out, bo, 192);
}

// Round 6
// 120.138 us; speedup vs baseline: 1.9803x; 1.3681x over previous
//
#include <hip/hip_runtime.h>
#include <hip/hip_bf16.h>

// B=16, H=64, W=64, C=192, heads=8, key_dim=32, ks=3
// pixels = 65536; model dim = 256.
// QKV row (stride 864 bf16): [ q(256) | kv-interleaved(512): g=0..63 -> k[4g..4g+3],v[4g..4g+3] | qb 8x12 (9 used) ]
// Zero row at pixel 65536 handles OOB neighbors (k'=v'=0 -> score=qb_n, v-bias via Ej/Ei fold).

typedef __bf16 bf16x8_t __attribute__((ext_vector_type(8)));
typedef float f32x4_t __attribute__((ext_vector_type(4)));

#define SCALE 0.17677669529663687f
#define QSTRIDE 864
#define ZROW 65536

static __device__ __forceinline__ unsigned short bfbits(float f) {
    return __builtin_bit_cast(unsigned short, __float2bfloat16(f));
}
static __device__ __forceinline__ float bf2f(unsigned short u) {
    return __bfloat162float(__builtin_bit_cast(__hip_bfloat16, u));
}
static __device__ __forceinline__ float lo16f(unsigned int u) {
    return __builtin_bit_cast(float, u << 16);
}
static __device__ __forceinline__ float hi16f(unsigned int u) {
    return __builtin_bit_cast(float, u & 0xffff0000u);
}

static __device__ __forceinline__ void gload_lds16(const void* g, void* l) {
    __builtin_amdgcn_global_load_lds((const __attribute__((address_space(1))) void*)g,
                                     (__attribute__((address_space(3))) void*)l, 16, 0, 0);
}

// ---------------------------------------------------------------- convert x -> bf16
__global__ void k_convert_x(const float* __restrict__ x, ushort4* __restrict__ xb, int n4) {
    int i = blockIdx.x * blockDim.x + threadIdx.x;
    const int stride = gridDim.x * blockDim.x;
    const float4* x4 = reinterpret_cast<const float4*>(x);
    for (; i < n4; i += stride) {
        float4 v = x4[i];
        ushort4 o;
        o.x = bfbits(v.x); o.y = bfbits(v.y); o.z = bfbits(v.z); o.w = bfbits(v.w);
        xb[i] = o;
    }
}

// ---------------------------------------------------------------- pack weights
// Composed QKV weight, columns permuted to the interleaved layout above.
// WqkvT[896][192] (cols 864..895 zero); qkvBias[896]; wvTab[3][256] = {Wv[192], Wv[193], bv}; zero QKV row.
__global__ void k_pack(const float* __restrict__ Wq, const float* __restrict__ Wk,
                       const float* __restrict__ Wv, const float* __restrict__ Wo,
                       const float* __restrict__ bq, const float* __restrict__ bk,
                       const float* __restrict__ bv,
                       __hip_bfloat16* __restrict__ WqkvT, __hip_bfloat16* __restrict__ WoT,
                       float* __restrict__ qkvBias, float* __restrict__ wvTab,
                       __hip_bfloat16* __restrict__ QKV) {
    const int idx = blockIdx.x * blockDim.x + threadIdx.x;
    const int T0 = 896 * 192;            // WqkvT
    const int T1 = T0 + 192 * 256;       // WoT
    const int T2 = T1 + 896;             // qkvBias
    const int T3 = T2 + 768;             // wvTab
    const int T4 = T3 + QSTRIDE;         // zero row
    if (idx < T0) {
        const int m = idx / 192, k = idx % 192;
        float v = 0.f;
        if (m < 256) {
            v = Wq[k * 256 + m] * SCALE;
        } else if (m < 768) {
            const int j = m - 256, g = j >> 3, r = j & 7;
            const int d = 4 * g + (r & 3);
            v = (r < 4) ? Wk[k * 256 + d] : Wv[k * 256 + d];
        } else if (m < 864) {
            const int j = m - 768, h = j / 12, n = j % 12;
            if (n < 9) {
                const float dj = (float)(n % 3 - 1), di = (float)(n / 3 - 1);
                float acc = 0.f;
                for (int d = 0; d < 32; ++d) {
                    const int c = h * 32 + d;
                    const float bkv = dj * Wk[192 * 256 + c] + di * Wk[193 * 256 + c] + bk[c];
                    acc += Wq[k * 256 + c] * bkv;
                }
                v = acc * SCALE;
            }
        }
        WqkvT[m * 192 + k] = __float2bfloat16(v);
    } else if (idx < T1) {
        const int j = idx - T0;
        const int c = j >> 8, hd = j & 255;
        WoT[j] = __float2bfloat16(Wo[hd * 192 + c]);
    } else if (idx < T2) {
        const int col = idx - T1;
        float v = 0.f;
        if (col < 256) v = bq[col] * SCALE;
        else if (col >= 768 && col < 864) {
            const int j = col - 768, h = j / 12, n = j % 12;
            if (n < 9) {
                const float dj = (float)(n % 3 - 1), di = (float)(n / 3 - 1);
                float acc = 0.f;
                for (int d = 0; d < 32; ++d) {
                    const int c = h * 32 + d;
                    const float bkv = dj * Wk[192 * 256 + c] + di * Wk[193 * 256 + c] + bk[c];
                    acc += bq[c] * bkv;
                }
                v = acc * SCALE;
            }
        }
        qkvBias[col] = v;
    } else if (idx < T3) {
        const int j = idx - T2;
        const int t = j >> 8, m = j & 255;
        float v;
        if (t == 0)      v = Wv[192 * 256 + m];
        else if (t == 1) v = Wv[193 * 256 + m];
        else             v = bv[m];
        wvTab[j] = v;
    } else if (idx < T4) {
        const int j = idx - T3;
        QKV[(size_t)ZROW * QSTRIDE + j] = __float2bfloat16(0.f);
    }
}

// ---------------------------------------------------------------- LDS-staged MFMA GEMM
// 1D grid, XCD-chunked swizzle: col-blocks sharing an A row-panel colocate on one XCD.
template<int BM, int BN, int WRN, int WCN, int KDIM, int NOUT, int NBX, bool OUTF32, bool BIAS>
__global__ __launch_bounds__(256) void k_gemm_lds(const __hip_bfloat16* __restrict__ A,
                          const __hip_bfloat16* __restrict__ BT,
                          void* __restrict__ Cout,
                          const float* __restrict__ bias, int ldc) {
    constexpr int WTR = BM / WRN;
    constexpr int WTC = BN / WCN;
    constexpr int FR = WTR / 16;
    constexpr int FC = WTC / 16;
    constexpr int NK = KDIM / 64;
    __shared__ __hip_bfloat16 sA[BM * 64];
    __shared__ __hip_bfloat16 sB[BN * 64];
    const int bid = blockIdx.x;
    const int s = (bid & 7) * ((int)gridDim.x >> 3) + (bid >> 3);
    const int by = s / NBX, bx = s - by * NBX;
    const int tid = threadIdx.x;
    const int wave = tid >> 6, lane = tid & 63;
    const int wr = wave / WCN, wc = wave % WCN;
    const long rowBase = (long)by * BM;
    const long colBase = (long)bx * BN;
    const int lr = lane & 15, lk = lane >> 4;
    const int srow = lane >> 3;
    const int scol = (lane & 7) * 8;

    f32x4_t acc[FR][FC] = {};
    for (int t = 0; t < NK; ++t) {
        const int k0 = t * 64;
        #pragma unroll
        for (int r = 0; r < BM / 32; ++r) {
            const int row0 = r * 32 + wave * 8;
            gload_lds16(A + (rowBase + row0 + srow) * KDIM + k0 + scol, sA + row0 * 64);
        }
        #pragma unroll
        for (int r = 0; r < BN / 32; ++r) {
            const int row0 = r * 32 + wave * 8;
            gload_lds16(BT + (colBase + row0 + srow) * KDIM + k0 + scol, sB + row0 * 64);
        }
        __syncthreads();
        #pragma unroll
        for (int kk = 0; kk < 64; kk += 32) {
            bf16x8_t a[FR], b[FC];
            #pragma unroll
            for (int fr = 0; fr < FR; ++fr)
                a[fr] = *reinterpret_cast<const bf16x8_t*>(sA + (wr * WTR + fr * 16 + lr) * 64 + kk + lk * 8);
            #pragma unroll
            for (int fc = 0; fc < FC; ++fc)
                b[fc] = *reinterpret_cast<const bf16x8_t*>(sB + (wc * WTC + fc * 16 + lr) * 64 + kk + lk * 8);
            #pragma unroll
            for (int fr = 0; fr < FR; ++fr) {
                #pragma unroll
                for (int fc = 0; fc < FC; ++fc)
                    acc[fr][fc] = __builtin_amdgcn_mfma_f32_16x16x32_bf16(a[fr], b[fc], acc[fr][fc], 0, 0, 0);
            }
        }
        __syncthreads();
    }
    const int rowSub = (lane >> 4) * 4;
    const int colSub = lane & 15;
    #pragma unroll
    for (int fr = 0; fr < FR; ++fr) {
        #pragma unroll
        for (int fc = 0; fc < FC; ++fc) {
            const long col = colBase + wc * WTC + fc * 16 + colSub;
            if (col >= NOUT) continue;
            float bvv = BIAS ? bias[col] : 0.f;
            #pragma unroll
            for (int r = 0; r < 4; ++r) {
                const long row = rowBase + wr * WTR + fr * 16 + rowSub + r;
                float v = acc[fr][fc][r] + bvv;
                if constexpr (OUTF32) ((float*)Cout)[row * ldc + col] = v;
                else ((__hip_bfloat16*)Cout)[row * ldc + col] = __float2bfloat16(v);
            }
        }
    }
}

// ---------------------------------------------------------------- attention gather
// One wave per pixel; lane (h=lane>>3, dg=lane&7) owns dims idx=h*32+dg*4.
// 9 neighbor gathers of 16B each: [k0..k3,v0..v3]. score_n = q.k_n + qb_n.
// o = inv*(sum_n p_n v_n + Ej*Wv192 + Ei*Wv193) + bv.
__global__ __launch_bounds__(256) void k_attn(const __hip_bfloat16* __restrict__ QKV,
                       const float* __restrict__ wvTab,
                       __hip_bfloat16* __restrict__ O) {
    const int wave = threadIdx.x >> 6;
    const int lane = threadIdx.x & 63;
    const int bid = blockIdx.x;
    const int sblk = (bid & 7) * 2048 + (bid >> 3);   // XCD-chunked swizzle (16384 wgs)
    const int p = sblk * 4 + wave;
    const int y = (p >> 6) & 63;
    const int xq = p & 63;
    const int h = lane >> 3, dg = lane & 7;
    const int idx = h * 32 + dg * 4;
    const __hip_bfloat16* rowQ = QKV + (size_t)p * QSTRIDE;

    const ushort4 qu = *reinterpret_cast<const ushort4*>(rowQ + idx);
    const float q0 = bf2f(qu.x), q1 = bf2f(qu.y), q2 = bf2f(qu.z), q3 = bf2f(qu.w);

    // qb: 9 values per head, padded to 12 -> 2x ushort4 + 1 scalar
    const ushort4 qba = *reinterpret_cast<const ushort4*>(rowQ + 768 + 12 * h);
    const ushort4 qbb = *reinterpret_cast<const ushort4*>(rowQ + 772 + 12 * h);
    const unsigned short qbc = *reinterpret_cast<const unsigned short*>(rowQ + 776 + 12 * h);
    float qb[9] = { bf2f(qba.x), bf2f(qba.y), bf2f(qba.z), bf2f(qba.w),
                    bf2f(qbb.x), bf2f(qbb.y), bf2f(qbb.z), bf2f(qbb.w), bf2f(qbc) };

    // branch-free neighbor gathers (OOB -> zero row), issued up front
    const char* baseQ = reinterpret_cast<const char*>(QKV);
    const long rowByte = (long)p * (QSTRIDE * 2);
    const int laneOff = 512 + 128 * h + 16 * dg;   // byte offset of this lane's kv group
    uint4 kv[9];
    #pragma unroll
    for (int n = 0; n < 9; ++n) {
        const int di = n / 3 - 1, dj = n % 3 - 1;
        const int ny = y + di, nx = xq + dj;
        const bool inb = ((unsigned)ny < 64u) & ((unsigned)nx < 64u);
        const long off = inb ? rowByte + (long)((di * 64 + dj) * (QSTRIDE * 2))
                             : (long)ZROW * (QSTRIDE * 2);
        kv[n] = *reinterpret_cast<const uint4*>(baseQ + off + laneOff);
    }

    float sc[9];
    #pragma unroll
    for (int n = 0; n < 9; ++n) {
        const float k0 = lo16f(kv[n].x), k1 = hi16f(kv[n].x);
        const float k2 = lo16f(kv[n].y), k3 = hi16f(kv[n].y);
        float ss = fmaf(q0, k0, fmaf(q1, k1, fmaf(q2, k2, q3 * k3)));
        ss += __shfl_xor(ss, 1);
        ss += __shfl_xor(ss, 2);
        ss += __shfl_xor(ss, 4);
        sc[n] = ss + qb[n];
    }
    float mx = sc[0];
    #pragma unroll
    for (int n = 1; n < 9; ++n) mx = fmaxf(mx, sc[n]);
    float sum = 0.f;
    #pragma unroll
    for (int n = 0; n < 9; ++n) { sc[n] = __expf(sc[n] - mx); sum += sc[n]; }
    const float inv = 1.0f / sum;
    const float Ej = (sc[2] + sc[5] + sc[8]) - (sc[0] + sc[3] + sc[6]);
    const float Ei = (sc[6] + sc[7] + sc[8]) - (sc[0] + sc[1] + sc[2]);

    float o0 = 0.f, o1 = 0.f, o2 = 0.f, o3 = 0.f;
    #pragma unroll
    for (int n = 0; n < 9; ++n) {
        o0 = fmaf(sc[n], lo16f(kv[n].z), o0);
        o1 = fmaf(sc[n], hi16f(kv[n].z), o1);
        o2 = fmaf(sc[n], lo16f(kv[n].w), o2);
        o3 = fmaf(sc[n], hi16f(kv[n].w), o3);
    }
    const float4 w0 = *reinterpret_cast<const float4*>(wvTab + idx);
    const float4 w1 = *reinterpret_cast<const float4*>(wvTab + 256 + idx);
    const float4 w2 = *reinterpret_cast<const float4*>(wvTab + 512 + idx);
    o0 = fmaf(Ej, w0.x, fmaf(Ei, w1.x, o0)) * inv + w2.x;
    o1 = fmaf(Ej, w0.y, fmaf(Ei, w1.y, o1)) * inv + w2.y;
    o2 = fmaf(Ej, w0.z, fmaf(Ei, w1.z, o2)) * inv + w2.z;
    o3 = fmaf(Ej, w0.w, fmaf(Ei, w1.w, o3)) * inv + w2.w;

    ushort4 ov;
    ov.x = bfbits(o0); ov.y = bfbits(o1); ov.z = bfbits(o2); ov.w = bfbits(o3);
    *reinterpret_cast<ushort4*>(O + (size_t)p * 256 + idx) = ov;
}

// ---------------------------------------------------------------- launch
extern "C" void kernel_launch(void* const* d_in, const int* in_sizes, int n_in,
                              void* d_out, int out_size, void* d_ws, size_t ws_size,
                              hipStream_t stream) {
    (void)in_sizes; (void)n_in; (void)out_size; (void)ws_size;
    const float* x  = (const float*)d_in[0];
    const float* Wq = (const float*)d_in[1];
    const float* bq = (const float*)d_in[2];
    const float* Wk = (const float*)d_in[3];
    const float* bk = (const float*)d_in[4];
    const float* Wv = (const float*)d_in[5];
    const float* bv = (const float*)d_in[6];
    const float* Wo = (const float*)d_in[7];
    const float* bo = (const float*)d_in[8];

    char* ws = (char*)d_ws;
    // ws layout (O overlaps dead xb; total ~147.3 MB):
    __hip_bfloat16* xb    = (__hip_bfloat16*)(ws + 0);           // 25,165,824 B
    __hip_bfloat16* O     = (__hip_bfloat16*)(ws + 0);           // 33,554,432 B (xb dead by then)
    __hip_bfloat16* QKV   = (__hip_bfloat16*)(ws + 33554432);    // 65537*864*2 = 113,247,936 B
    __hip_bfloat16* WqkvT = (__hip_bfloat16*)(ws + 146802368);   // 896*192*2 = 344,064
    __hip_bfloat16* WoT   = (__hip_bfloat16*)(ws + 147146432);   // 192*256*2 = 98,304
    float* qkvBias        = (float*)(ws + 147244736);            // 896*4 = 3,584
    float* wvTab          = (float*)(ws + 147248320);            // 3*256*4 = 3,072

    k_convert_x<<<4096, 256, 0, stream>>>(x, (ushort4*)xb, 12582912 / 4);
    k_pack<<<874, 256, 0, stream>>>(Wq, Wk, Wv, Wo, bq, bk, bv, WqkvT, WoT, qkvBias, wvTab, QKV);
    // QKV+QB projection: [65536,192] x [192,896(864 used)] -> bf16, stride 864
    k_gemm_lds<128, 128, 2, 2, 192, 864, 7, false, true>
        <<<3584, 256, 0, stream>>>(xb, WqkvT, (void*)QKV, qkvBias, QSTRIDE);
    // attention: one wave per pixel
    k_attn<<<16384, 256, 0, stream>>>(QKV, wvTab, O);
    // output projection: [65536,256] x [256,192] -> f32 + bo
    k_gemm_lds<128, 64, 2, 2, 256, 192, 3, true, true>
        <<<1536, 256, 0, stream>>>(O, WoT, d_out, bo, 192);
}